// Round 11
// baseline (236.634 us; speedup 1.0000x reference)
//
#include <hip/hip_runtime.h>
#include <hip/hip_bf16.h>
#include <stdint.h>

using bf16 = __hip_bfloat16;
typedef float v4f __attribute__((ext_vector_type(4)));
typedef short short8 __attribute__((ext_vector_type(8)));

// Shapes (fixed): B=32, L=S=96, D=512, H=8, DH=64, d_ff=9216. M = B*L = 3072.

// ---- async global->LDS 16B (wave-uniform LDS base + lane*16) ---------------
__device__ __forceinline__ void async_cp16(void* l, const void* g) {
  __builtin_amdgcn_global_load_lds(
      (const __attribute__((address_space(1))) void*)(uintptr_t)g,
      (__attribute__((address_space(3))) void*)(uintptr_t)l, 16, 0, 0);
}

// ---- prep: all transposes + X f32->bf16 + out bias-init, one launch --------
__global__ __launch_bounds__(256) void prep(
    const float* __restrict__ Wo, const float* __restrict__ Wq,
    const float* __restrict__ Wk, const float* __restrict__ Wv,
    const float* __restrict__ Xq, const float* __restrict__ Xk,
    const float* __restrict__ Xv, const float* __restrict__ bo,
    bf16* __restrict__ WoT, bf16* __restrict__ WTq,
    bf16* __restrict__ WTk, bf16* __restrict__ WTv,
    bf16* __restrict__ Xbq, bf16* __restrict__ Xbk, bf16* __restrict__ Xbv,
    float* __restrict__ out) {
  const int bid = blockIdx.x, t = threadIdx.x;
  if (bid < 5376) {                       // transpose f32 -> bf16
    __shared__ bf16 T[32][33];
    const float* src; bf16* dst; int K, N, kx, ny;
    if (bid < 4608) {                     // Wo: 288 x 16 tiles
      src = Wo; dst = WoT; K = 9216; N = 512; kx = bid % 288; ny = bid / 288;
    } else {
      const int r = bid - 4608, which = r >> 8, rr = r & 255;
      kx = rr & 15; ny = rr >> 4; K = 512; N = 512;
      src = which == 0 ? Wq : (which == 1 ? Wk : Wv);
      dst = which == 0 ? WTq : (which == 1 ? WTk : WTv);
    }
    const int k0 = kx * 32, n0 = ny * 32;
    const int r = t >> 3, c = (t & 7) * 4;
    float4 v = *reinterpret_cast<const float4*>(src + (size_t)(k0 + r) * N + n0 + c);
    T[c + 0][r] = __float2bfloat16(v.x);
    T[c + 1][r] = __float2bfloat16(v.y);
    T[c + 2][r] = __float2bfloat16(v.z);
    T[c + 3][r] = __float2bfloat16(v.w);
    __syncthreads();
    union { uint2 u; bf16 h[4]; } o;
    o.h[0] = T[r][c + 0]; o.h[1] = T[r][c + 1];
    o.h[2] = T[r][c + 2]; o.h[3] = T[r][c + 3];
    *reinterpret_cast<uint2*>(dst + (size_t)(n0 + r) * K + k0 + c) = o.u;
  } else if (bid < 6528) {                // X f32 -> bf16 (16 elems/thread)
    const int r = bid - 5376;
    const int which = r / 384, blk = r % 384;
    const float* src = which == 0 ? Xq : (which == 1 ? Xk : Xv);
    bf16* dst = which == 0 ? Xbq : (which == 1 ? Xbk : Xbv);
    const int base = blk * 4096 + t * 16;
    float4 a = *reinterpret_cast<const float4*>(src + base);
    float4 b = *reinterpret_cast<const float4*>(src + base + 4);
    float4 c = *reinterpret_cast<const float4*>(src + base + 8);
    float4 d = *reinterpret_cast<const float4*>(src + base + 12);
    union { uint4 u; bf16 h[8]; } o1, o2;
    o1.h[0] = __float2bfloat16(a.x); o1.h[1] = __float2bfloat16(a.y);
    o1.h[2] = __float2bfloat16(a.z); o1.h[3] = __float2bfloat16(a.w);
    o1.h[4] = __float2bfloat16(b.x); o1.h[5] = __float2bfloat16(b.y);
    o1.h[6] = __float2bfloat16(b.z); o1.h[7] = __float2bfloat16(b.w);
    o2.h[0] = __float2bfloat16(c.x); o2.h[1] = __float2bfloat16(c.y);
    o2.h[2] = __float2bfloat16(c.z); o2.h[3] = __float2bfloat16(c.w);
    o2.h[4] = __float2bfloat16(d.x); o2.h[5] = __float2bfloat16(d.y);
    o2.h[6] = __float2bfloat16(d.z); o2.h[7] = __float2bfloat16(d.w);
    *reinterpret_cast<uint4*>(dst + base) = o1.u;
    *reinterpret_cast<uint4*>(dst + base + 8) = o2.u;
  } else {                                // init out with bias
    const int r = bid - 6528;
    const int idx = (r * 256 + t) * 4;    // < 3072*512
    *reinterpret_cast<float4*>(out + idx) =
        *reinterpret_cast<const float4*>(bo + (idx & 511));
  }
}

// ---- fused Q/K/V projections: B-only LDS, A register-direct ----------------
// 64x64 tile, 2 waves (each 32 rows x 64 cols), BK=128, K=512 (4 steps).
// z==0 folds core[n,h]/8 into output (raw-reshape: n=row/384, h=col&63).
// Bs rows: 128 bf16 = 16 chunks; phys chunk = logical ^ (row & 7)
__global__ __launch_bounds__(128) void proj_mfma(
    const bf16* __restrict__ Xb0, const bf16* __restrict__ Xb1,
    const bf16* __restrict__ Xb2,
    const bf16* __restrict__ WT0, const bf16* __restrict__ WT1,
    const bf16* __restrict__ WT2,
    const float* __restrict__ b0, const float* __restrict__ b1,
    const float* __restrict__ b2, const float* __restrict__ core,
    bf16* __restrict__ O0, bf16* __restrict__ O1, bf16* __restrict__ O2) {
  const int z = blockIdx.z;
  const bf16* X    = z == 0 ? Xb0 : (z == 1 ? Xb1 : Xb2);
  const bf16* WT   = z == 0 ? WT0 : (z == 1 ? WT1 : WT2);
  const float* bia = z == 0 ? b0 : (z == 1 ? b1 : b2);
  bf16* O          = z == 0 ? O0 : (z == 1 ? O1 : O2);

  const int bm = blockIdx.x * 64, bn = blockIdx.y * 64;
  __shared__ __align__(16) bf16 Bs[64 * 128];    // 16 KB
  const int t = threadIdx.x;
  const int w = t >> 6, lane = t & 63;
  const int m16 = lane & 15, q = lane >> 4;
  const int l16 = lane >> 4, l15 = lane & 15;

  v4f acc[2][4] = {};

  for (int k0 = 0; k0 < 512; k0 += 128) {
    __syncthreads();
    #pragma unroll
    for (int c = 0; c < 8; c++) {                // B: 8 calls/wave, 4 rows each
      const int row = (w * 8 + c) * 4 + l16;
      const int lch = l15 ^ (row & 7);
      async_cp16(&Bs[(w * 8 + c) * 512],
                 WT + (size_t)(bn + row) * 512 + k0 + lch * 8);
    }
    __syncthreads();

    #pragma unroll
    for (int s = 0; s < 4; s++) {
      const int kof = k0 + s * 32 + q * 8;
      short8 af[2], bfr[4];
      #pragma unroll
      for (int mt = 0; mt < 2; mt++)
        af[mt] = *reinterpret_cast<const short8*>(
            X + (size_t)(bm + w * 32 + mt * 16 + m16) * 512 + kof);
      const int pc = ((s * 4 + q) ^ (m16 & 7)) * 8;
      #pragma unroll
      for (int nt = 0; nt < 4; nt++)
        bfr[nt] = *reinterpret_cast<const short8*>(
            &Bs[(nt * 16 + m16) * 128 + pc]);
      #pragma unroll
      for (int mt = 0; mt < 2; mt++)
        #pragma unroll
        for (int nt = 0; nt < 4; nt++)
          acc[mt][nt] = __builtin_amdgcn_mfma_f32_16x16x32_bf16(
              af[mt], bfr[nt], acc[mt][nt], 0, 0, 0);
    }
  }

  const bool isQ = (z == 0);
  const int nblk = bm / 384;   // 64 | 384 so head index is block-uniform
  #pragma unroll
  for (int mt = 0; mt < 2; mt++)
    #pragma unroll
    for (int nt = 0; nt < 4; nt++)
      #pragma unroll
      for (int r = 0; r < 4; r++) {
        const int row = bm + w * 32 + mt * 16 + q * 4 + r;
        const int col = bn + nt * 16 + m16;
        float v = acc[mt][nt][r] + bia[col];
        if (isQ) v *= core[nblk * 64 + (col & 63)] * 0.125f;
        O[(size_t)row * 512 + col] = __float2bfloat16(v);
      }
}

// ------------- stage B (R6/R9 proven: MFMA, TI=2, async V, swizzled LDS) ----
// raw-reshape indexing: aq/k/v[n,b,i,h] = P[n*196608 + b*6144 + i*64 + h]
// LDS rows: 64 bf16 = 128 B, phys chunk = logical chunk ^ (row & 7)
__global__ __launch_bounds__(256) void stage_b_mfma(
    const bf16* __restrict__ AQ, const bf16* __restrict__ KPb,
    const bf16* __restrict__ VPb, bf16* __restrict__ FULL) {
  const int b = blockIdx.y;
  const int i0 = blockIdx.x * 2;

  __shared__ __align__(16) bf16 smem[19456];  // Ks0|Ks1|Vs|aq2 ; epi: 2x9216
  bf16* Ks0 = smem;            // 6144 (96x64 swizzled)
  bf16* Ks1 = smem + 6144;
  bf16* Vs  = smem + 12288;
  bf16* aqs = smem + 18432;    // 2 x 512

  const int t = threadIdx.x;
  const int w = t >> 6, lane = t & 63;
  const int wr = w >> 1, wc = w & 1;    // 2x2 waves, each 48x48 region
  const int m16 = lane & 15, q = lane >> 4;
  const int l8 = lane >> 3, l7 = lane & 7;

  if (t < 128) {                         // load aq rows for both i
    const int isel = t & 1, n = t >> 4, seg = (t >> 1) & 7;
    *reinterpret_cast<uint4*>(&aqs[isel * 512 + n * 64 + seg * 8]) =
        *reinterpret_cast<const uint4*>(
            AQ + (size_t)n * 196608 + b * 6144 + (i0 + isel) * 64 + seg * 8);
  }

  union U8 { uint4 u; bf16 h[8]; };
  const int colq = (t & 7) * 8;          // k-column of this thread's K chunks
  const int rowk = t >> 3;               // base K row (+32 per chunk iter)
  const int krow7 = rowk & 7;

  U8 kk[3];
  {
    const bf16* Kp = KPb + b * 6144;     // n = 0 slab
    #pragma unroll
    for (int c3 = 0; c3 < 3; c3++)
      kk[c3].u = *reinterpret_cast<const uint4*>(Kp + (t + c3 * 256) * 8);
  }

  v4f acc[2][3][3] = {};

  for (int n = 0; n < 8; n++) {
    __syncthreads();                     // prev frag reads done; aqs ready
    // async V staging (swizzled): 3 calls/wave, 8 rows each
    const bf16* Vp = VPb + (size_t)n * 196608 + b * 6144;
    #pragma unroll
    for (int c = 0; c < 3; c++) {
      const int r0 = (w * 3 + c) * 8;
      async_cp16(&Vs[(w * 3 + c) * 512],
                 Vp + (r0 + l8) * 64 + (l7 ^ l8) * 8);
    }
    // aq scales for this n (f32, hoisted)
    float a0f[8], a1f[8];
    {
      U8 a0, a1;
      a0.u = *reinterpret_cast<const uint4*>(&aqs[n * 64 + colq]);
      a1.u = *reinterpret_cast<const uint4*>(&aqs[512 + n * 64 + colq]);
      #pragma unroll
      for (int e = 0; e < 8; e++) {
        a0f[e] = __bfloat162float(a0.h[e]);
        a1f[e] = __bfloat162float(a1.h[e]);
      }
    }
    // repack K with per-i scales into swizzled LDS
    #pragma unroll
    for (int c3 = 0; c3 < 3; c3++) {
      U8 s0, s1;
      #pragma unroll
      for (int e = 0; e < 8; e++) {
        const float kv = __bfloat162float(kk[c3].h[e]);
        s0.h[e] = __float2bfloat16(kv * a0f[e]);
        s1.h[e] = __float2bfloat16(kv * a1f[e]);
      }
      const int phys = (rowk + 32 * c3) * 64 + (l7 ^ krow7) * 8;
      *reinterpret_cast<uint4*>(&Ks0[phys]) = s0.u;
      *reinterpret_cast<uint4*>(&Ks1[phys]) = s1.u;
    }
    __syncthreads();                     // drains async V + K writes
    // prefetch next n's K slab (latency hides behind MFMAs)
    if (n < 7) {
      const bf16* Kp1 = KPb + (size_t)(n + 1) * 196608 + b * 6144;
      #pragma unroll
      for (int c3 = 0; c3 < 3; c3++)
        kk[c3].u = *reinterpret_cast<const uint4*>(Kp1 + (t + c3 * 256) * 8);
    }

    #pragma unroll
    for (int s = 0; s < 2; s++) {
      const int pc = ((s * 4 + q) ^ (m16 & 7)) * 8;
      short8 bfr[3], af0[3], af1[3];
      #pragma unroll
      for (int cc = 0; cc < 3; cc++)
        bfr[cc] = *reinterpret_cast<const short8*>(
            &Vs[(wc * 48 + cc * 16 + m16) * 64 + pc]);
      #pragma unroll
      for (int a = 0; a < 3; a++) {
        af0[a] = *reinterpret_cast<const short8*>(
            &Ks0[(wr * 48 + a * 16 + m16) * 64 + pc]);
        af1[a] = *reinterpret_cast<const short8*>(
            &Ks1[(wr * 48 + a * 16 + m16) * 64 + pc]);
      }
      #pragma unroll
      for (int a = 0; a < 3; a++)
        #pragma unroll
        for (int cc = 0; cc < 3; cc++) {
          acc[0][a][cc] = __builtin_amdgcn_mfma_f32_16x16x32_bf16(
              af0[a], bfr[cc], acc[0][a][cc], 0, 0, 0);
          acc[1][a][cc] = __builtin_amdgcn_mfma_f32_16x16x32_bf16(
              af1[a], bfr[cc], acc[1][a][cc], 0, 0, 0);
        }
    }
  }

  // epilogue: assemble rows in LDS, then coalesced 16B global stores
  __syncthreads();
  #pragma unroll
  for (int isel = 0; isel < 2; isel++)
    #pragma unroll
    for (int a = 0; a < 3; a++)
      #pragma unroll
      for (int cc = 0; cc < 3; cc++) {
        const int j0 = wr * 48 + a * 16, k0c = wc * 48 + cc * 16;
        #pragma unroll
        for (int r = 0; r < 4; r++)
          smem[isel * 9216 + (j0 + q * 4 + r) * 96 + k0c + m16] =
              __float2bfloat16(acc[isel][a][cc][r]);
      }
  __syncthreads();
  const size_t obase = (size_t)(b * 96 + i0) * 9216;
  #pragma unroll
  for (int c = t; c < 2304; c += 256)
    *reinterpret_cast<uint4*>(FULL + obase + c * 8) =
        *reinterpret_cast<const uint4*>(&smem[c * 8]);
}

// ------- stage C: B-only LDS, A register-direct, 64x64/2-wave, split-K=4 ----
// Bs rows: 128 bf16 = 16 chunks; phys chunk = logical ^ (row & 7)
__global__ __launch_bounds__(128) void stage_c_mfma(
    const bf16* __restrict__ FULL, const bf16* __restrict__ WoT,
    float* __restrict__ out) {
  const int bm = blockIdx.x * 64, bn = blockIdx.y * 64;
  const int kbase = blockIdx.z * 2304;
  __shared__ __align__(16) bf16 Bs[64 * 128];    // 16 KB
  const int t = threadIdx.x;
  const int w = t >> 6, lane = t & 63;
  const int m16 = lane & 15, q = lane >> 4;
  const int l16 = lane >> 4, l15 = lane & 15;

  v4f acc[2][4] = {};

  for (int k0 = kbase; k0 < kbase + 2304; k0 += 128) {
    __syncthreads();
    #pragma unroll
    for (int c = 0; c < 8; c++) {                // B: 8 calls/wave, 4 rows each
      const int row = (w * 8 + c) * 4 + l16;
      const int lch = l15 ^ (row & 7);
      async_cp16(&Bs[(w * 8 + c) * 512],
                 WoT + (size_t)(bn + row) * 9216 + k0 + lch * 8);
    }
    __syncthreads();

    #pragma unroll
    for (int s = 0; s < 4; s++) {
      const int kof = k0 + s * 32 + q * 8;
      short8 af[2], bfr[4];
      #pragma unroll
      for (int mt = 0; mt < 2; mt++)
        af[mt] = *reinterpret_cast<const short8*>(
            FULL + (size_t)(bm + w * 32 + mt * 16 + m16) * 9216 + kof);
      const int pc = ((s * 4 + q) ^ (m16 & 7)) * 8;
      #pragma unroll
      for (int nt = 0; nt < 4; nt++)
        bfr[nt] = *reinterpret_cast<const short8*>(
            &Bs[(nt * 16 + m16) * 128 + pc]);
      #pragma unroll
      for (int mt = 0; mt < 2; mt++)
        #pragma unroll
        for (int nt = 0; nt < 4; nt++)
          acc[mt][nt] = __builtin_amdgcn_mfma_f32_16x16x32_bf16(
              af[mt], bfr[nt], acc[mt][nt], 0, 0, 0);
    }
  }

  #pragma unroll
  for (int mt = 0; mt < 2; mt++)
    #pragma unroll
    for (int nt = 0; nt < 4; nt++)
      #pragma unroll
      for (int r = 0; r < 4; r++) {
        const int row = bm + w * 32 + mt * 16 + q * 4 + r;
        const int col = bn + nt * 16 + m16;
        atomicAdd(&out[(size_t)row * 512 + col], acc[mt][nt][r]);
      }
}

extern "C" void kernel_launch(void* const* d_in, const int* in_sizes, int n_in,
                              void* d_out, int out_size, void* d_ws, size_t ws_size,
                              hipStream_t stream) {
  const float* queries = (const float*)d_in[0];
  const float* keys    = (const float*)d_in[1];
  const float* values  = (const float*)d_in[2];
  // d_in[3] = attn_mask (unused by reference)
  const float* Wq   = (const float*)d_in[4];
  const float* bq   = (const float*)d_in[5];
  const float* Wk   = (const float*)d_in[6];
  const float* bk   = (const float*)d_in[7];
  const float* Wv   = (const float*)d_in[8];
  const float* bv   = (const float*)d_in[9];
  const float* core = (const float*)d_in[10];
  const float* Wo   = (const float*)d_in[11];
  const float* bo   = (const float*)d_in[12];
  float* out = (float*)d_out;

  char* ws = (char*)d_ws;
  bf16* AQb = (bf16*)(ws);                   // 3.15 MB (3072*512) = core*q/8
  bf16* KPb = (bf16*)(ws + 3145728);         // 3.15 MB
  bf16* VPb = (bf16*)(ws + 6291456);         // 3.15 MB
  bf16* WTq = (bf16*)(ws + 9437184);         // 0.52 MB (512*512)
  bf16* WTk = (bf16*)(ws + 9961472);         // 0.52 MB
  bf16* WTv = (bf16*)(ws + 10485760);        // 0.52 MB
  bf16* WoT = (bf16*)(ws + 11010048);        // 9.44 MB (512*9216)
  bf16* FULL = (bf16*)(ws + 20447232);       // 56.62 MB (3072*9216)
  // Xb* overlay the FULL region: proj reads them before stage_b writes FULL.
  bf16* Xbq = FULL;
  bf16* Xbk = FULL + 1572864;
  bf16* Xbv = FULL + 3145728;

  prep<<<dim3(8064), dim3(256), 0, stream>>>(
      Wo, Wq, Wk, Wv, queries, keys, values, bo,
      WoT, WTq, WTk, WTv, Xbq, Xbk, Xbv, out);

  proj_mfma<<<dim3(48, 8, 3), dim3(128), 0, stream>>>(
      Xbq, Xbk, Xbv, WTq, WTk, WTv, bq, bk, bv, core, AQb, KPb, VPb);

  stage_b_mfma<<<dim3(48, 32), dim3(256), 0, stream>>>(AQb, KPb, VPb, FULL);

  stage_c_mfma<<<dim3(48, 8, 4), dim3(128), 0, stream>>>(FULL, WoT, out);
}

// Round 12
// 202.622 us; speedup vs baseline: 1.1679x; 1.1679x over previous
//
#include <hip/hip_runtime.h>
#include <hip/hip_bf16.h>
#include <stdint.h>

using bf16 = __hip_bfloat16;
typedef float v4f __attribute__((ext_vector_type(4)));
typedef short short8 __attribute__((ext_vector_type(8)));

// Shapes (fixed): B=32, L=S=96, D=512, H=8, DH=64, d_ff=9216. M = B*L = 3072.

// ---- async global->LDS 16B (wave-uniform LDS base + lane*16) ---------------
__device__ __forceinline__ void async_cp16(void* l, const void* g) {
  __builtin_amdgcn_global_load_lds(
      (const __attribute__((address_space(1))) void*)(uintptr_t)g,
      (__attribute__((address_space(3))) void*)(uintptr_t)l, 16, 0, 0);
}

// ---- prep: all transposes + X f32->bf16 + out bias-init, one launch --------
__global__ __launch_bounds__(256) void prep(
    const float* __restrict__ Wo, const float* __restrict__ Wq,
    const float* __restrict__ Wk, const float* __restrict__ Wv,
    const float* __restrict__ Xq, const float* __restrict__ Xk,
    const float* __restrict__ Xv, const float* __restrict__ bo,
    bf16* __restrict__ WoT, bf16* __restrict__ WTq,
    bf16* __restrict__ WTk, bf16* __restrict__ WTv,
    bf16* __restrict__ Xbq, bf16* __restrict__ Xbk, bf16* __restrict__ Xbv,
    float* __restrict__ out) {
  const int bid = blockIdx.x, t = threadIdx.x;
  if (bid < 5376) {                       // transpose f32 -> bf16
    __shared__ bf16 T[32][33];
    const float* src; bf16* dst; int K, N, kx, ny;
    if (bid < 4608) {                     // Wo: 288 x 16 tiles
      src = Wo; dst = WoT; K = 9216; N = 512; kx = bid % 288; ny = bid / 288;
    } else {
      const int r = bid - 4608, which = r >> 8, rr = r & 255;
      kx = rr & 15; ny = rr >> 4; K = 512; N = 512;
      src = which == 0 ? Wq : (which == 1 ? Wk : Wv);
      dst = which == 0 ? WTq : (which == 1 ? WTk : WTv);
    }
    const int k0 = kx * 32, n0 = ny * 32;
    const int r = t >> 3, c = (t & 7) * 4;
    float4 v = *reinterpret_cast<const float4*>(src + (size_t)(k0 + r) * N + n0 + c);
    T[c + 0][r] = __float2bfloat16(v.x);
    T[c + 1][r] = __float2bfloat16(v.y);
    T[c + 2][r] = __float2bfloat16(v.z);
    T[c + 3][r] = __float2bfloat16(v.w);
    __syncthreads();
    union { uint2 u; bf16 h[4]; } o;
    o.h[0] = T[r][c + 0]; o.h[1] = T[r][c + 1];
    o.h[2] = T[r][c + 2]; o.h[3] = T[r][c + 3];
    *reinterpret_cast<uint2*>(dst + (size_t)(n0 + r) * K + k0 + c) = o.u;
  } else if (bid < 6528) {                // X f32 -> bf16 (16 elems/thread)
    const int r = bid - 5376;
    const int which = r / 384, blk = r % 384;
    const float* src = which == 0 ? Xq : (which == 1 ? Xk : Xv);
    bf16* dst = which == 0 ? Xbq : (which == 1 ? Xbk : Xbv);
    const int base = blk * 4096 + t * 16;
    float4 a = *reinterpret_cast<const float4*>(src + base);
    float4 b = *reinterpret_cast<const float4*>(src + base + 4);
    float4 c = *reinterpret_cast<const float4*>(src + base + 8);
    float4 d = *reinterpret_cast<const float4*>(src + base + 12);
    union { uint4 u; bf16 h[8]; } o1, o2;
    o1.h[0] = __float2bfloat16(a.x); o1.h[1] = __float2bfloat16(a.y);
    o1.h[2] = __float2bfloat16(a.z); o1.h[3] = __float2bfloat16(a.w);
    o1.h[4] = __float2bfloat16(b.x); o1.h[5] = __float2bfloat16(b.y);
    o1.h[6] = __float2bfloat16(b.z); o1.h[7] = __float2bfloat16(b.w);
    o2.h[0] = __float2bfloat16(c.x); o2.h[1] = __float2bfloat16(c.y);
    o2.h[2] = __float2bfloat16(c.z); o2.h[3] = __float2bfloat16(c.w);
    o2.h[4] = __float2bfloat16(d.x); o2.h[5] = __float2bfloat16(d.y);
    o2.h[6] = __float2bfloat16(d.z); o2.h[7] = __float2bfloat16(d.w);
    *reinterpret_cast<uint4*>(dst + base) = o1.u;
    *reinterpret_cast<uint4*>(dst + base + 8) = o2.u;
  } else {                                // init out with bias
    const int r = bid - 6528;
    const int idx = (r * 256 + t) * 4;    // < 3072*512
    *reinterpret_cast<float4*>(out + idx) =
        *reinterpret_cast<const float4*>(bo + (idx & 511));
  }
}

// ---- fused Q/K/V projections (R10 proven): 128x64, BK=128, async swizzled --
// z==0 folds core[n,h]/8 into the output (raw-reshape: n=row/384, h=col&63).
// LDS rows: 128 bf16 = 256 B, phys chunk = logical chunk ^ (row & 7)
__global__ __launch_bounds__(256) void proj_mfma(
    const bf16* __restrict__ Xb0, const bf16* __restrict__ Xb1,
    const bf16* __restrict__ Xb2,
    const bf16* __restrict__ WT0, const bf16* __restrict__ WT1,
    const bf16* __restrict__ WT2,
    const float* __restrict__ b0, const float* __restrict__ b1,
    const float* __restrict__ b2, const float* __restrict__ core,
    bf16* __restrict__ O0, bf16* __restrict__ O1, bf16* __restrict__ O2) {
  const int z = blockIdx.z;
  const bf16* X    = z == 0 ? Xb0 : (z == 1 ? Xb1 : Xb2);
  const bf16* WT   = z == 0 ? WT0 : (z == 1 ? WT1 : WT2);
  const float* bia = z == 0 ? b0 : (z == 1 ? b1 : b2);
  bf16* O          = z == 0 ? O0 : (z == 1 ? O1 : O2);

  const int bm = blockIdx.x * 128, bn = blockIdx.y * 64;
  __shared__ __align__(16) bf16 As[128 * 128];   // 32 KB
  __shared__ __align__(16) bf16 Bs[64 * 128];    // 16 KB
  const int t = threadIdx.x;
  const int w = t >> 6, lane = t & 63;
  const int m16 = lane & 15, q = lane >> 4;
  const int l16 = lane >> 4, l15 = lane & 15;

  v4f acc[2][4] = {};

  for (int k0 = 0; k0 < 512; k0 += 128) {
    __syncthreads();
    #pragma unroll
    for (int c = 0; c < 8; c++) {                // A: 8 calls/wave, 4 rows each
      const int row = (w * 8 + c) * 4 + l16;
      const int lch = l15 ^ (row & 7);
      async_cp16(&As[(w * 8 + c) * 512],
                 X + (size_t)(bm + row) * 512 + k0 + lch * 8);
    }
    #pragma unroll
    for (int c = 0; c < 4; c++) {                // B: 4 calls/wave
      const int row = (w * 4 + c) * 4 + l16;
      const int lch = l15 ^ (row & 7);
      async_cp16(&Bs[(w * 4 + c) * 512],
                 WT + (size_t)(bn + row) * 512 + k0 + lch * 8);
    }
    __syncthreads();

    #pragma unroll
    for (int s = 0; s < 4; s++) {
      const int pc = ((s * 4 + q) ^ (m16 & 7)) * 8;
      short8 af[2], bfr[4];
      #pragma unroll
      for (int mt = 0; mt < 2; mt++)
        af[mt] = *reinterpret_cast<const short8*>(
            &As[(w * 32 + mt * 16 + m16) * 128 + pc]);
      #pragma unroll
      for (int nt = 0; nt < 4; nt++)
        bfr[nt] = *reinterpret_cast<const short8*>(
            &Bs[(nt * 16 + m16) * 128 + pc]);
      #pragma unroll
      for (int mt = 0; mt < 2; mt++)
        #pragma unroll
        for (int nt = 0; nt < 4; nt++)
          acc[mt][nt] = __builtin_amdgcn_mfma_f32_16x16x32_bf16(
              af[mt], bfr[nt], acc[mt][nt], 0, 0, 0);
    }
  }

  const bool isQ = (z == 0);
  const int nblk = bm / 384;   // 128 | 384 so head index is tile-uniform
  #pragma unroll
  for (int mt = 0; mt < 2; mt++)
    #pragma unroll
    for (int nt = 0; nt < 4; nt++)
      #pragma unroll
      for (int r = 0; r < 4; r++) {
        const int row = bm + w * 32 + mt * 16 + q * 4 + r;
        const int col = bn + nt * 16 + m16;
        float v = acc[mt][nt][r] + bia[col];
        if (isQ) v *= core[nblk * 64 + (col & 63)] * 0.125f;
        O[(size_t)row * 512 + col] = __float2bfloat16(v);
      }
}

// ------------- stage B (R6/R9/R10 proven: MFMA, TI=2, async V, swizzled) ----
// raw-reshape indexing: aq/k/v[n,b,i,h] = P[n*196608 + b*6144 + i*64 + h]
// LDS rows: 64 bf16 = 128 B, phys chunk = logical chunk ^ (row & 7)
__global__ __launch_bounds__(256) void stage_b_mfma(
    const bf16* __restrict__ AQ, const bf16* __restrict__ KPb,
    const bf16* __restrict__ VPb, bf16* __restrict__ FULL) {
  const int b = blockIdx.y;
  const int i0 = blockIdx.x * 2;

  __shared__ __align__(16) bf16 smem[19456];  // Ks0|Ks1|Vs|aq2 ; epi: 2x9216
  bf16* Ks0 = smem;            // 6144 (96x64 swizzled)
  bf16* Ks1 = smem + 6144;
  bf16* Vs  = smem + 12288;
  bf16* aqs = smem + 18432;    // 2 x 512

  const int t = threadIdx.x;
  const int w = t >> 6, lane = t & 63;
  const int wr = w >> 1, wc = w & 1;    // 2x2 waves, each 48x48 region
  const int m16 = lane & 15, q = lane >> 4;
  const int l8 = lane >> 3, l7 = lane & 7;

  if (t < 128) {                         // load aq rows for both i
    const int isel = t & 1, n = t >> 4, seg = (t >> 1) & 7;
    *reinterpret_cast<uint4*>(&aqs[isel * 512 + n * 64 + seg * 8]) =
        *reinterpret_cast<const uint4*>(
            AQ + (size_t)n * 196608 + b * 6144 + (i0 + isel) * 64 + seg * 8);
  }

  union U8 { uint4 u; bf16 h[8]; };
  const int colq = (t & 7) * 8;          // k-column of this thread's K chunks
  const int rowk = t >> 3;               // base K row (+32 per chunk iter)
  const int krow7 = rowk & 7;

  U8 kk[3];
  {
    const bf16* Kp = KPb + b * 6144;     // n = 0 slab
    #pragma unroll
    for (int c3 = 0; c3 < 3; c3++)
      kk[c3].u = *reinterpret_cast<const uint4*>(Kp + (t + c3 * 256) * 8);
  }

  v4f acc[2][3][3] = {};

  for (int n = 0; n < 8; n++) {
    __syncthreads();                     // prev frag reads done; aqs ready
    // async V staging (swizzled): 3 calls/wave, 8 rows each
    const bf16* Vp = VPb + (size_t)n * 196608 + b * 6144;
    #pragma unroll
    for (int c = 0; c < 3; c++) {
      const int r0 = (w * 3 + c) * 8;
      async_cp16(&Vs[(w * 3 + c) * 512],
                 Vp + (r0 + l8) * 64 + (l7 ^ l8) * 8);
    }
    // aq scales for this n (f32, hoisted)
    float a0f[8], a1f[8];
    {
      U8 a0, a1;
      a0.u = *reinterpret_cast<const uint4*>(&aqs[n * 64 + colq]);
      a1.u = *reinterpret_cast<const uint4*>(&aqs[512 + n * 64 + colq]);
      #pragma unroll
      for (int e = 0; e < 8; e++) {
        a0f[e] = __bfloat162float(a0.h[e]);
        a1f[e] = __bfloat162float(a1.h[e]);
      }
    }
    // repack K with per-i scales into swizzled LDS
    #pragma unroll
    for (int c3 = 0; c3 < 3; c3++) {
      U8 s0, s1;
      #pragma unroll
      for (int e = 0; e < 8; e++) {
        const float kv = __bfloat162float(kk[c3].h[e]);
        s0.h[e] = __float2bfloat16(kv * a0f[e]);
        s1.h[e] = __float2bfloat16(kv * a1f[e]);
      }
      const int phys = (rowk + 32 * c3) * 64 + (l7 ^ krow7) * 8;
      *reinterpret_cast<uint4*>(&Ks0[phys]) = s0.u;
      *reinterpret_cast<uint4*>(&Ks1[phys]) = s1.u;
    }
    __syncthreads();                     // drains async V + K writes
    // prefetch next n's K slab (latency hides behind MFMAs)
    if (n < 7) {
      const bf16* Kp1 = KPb + (size_t)(n + 1) * 196608 + b * 6144;
      #pragma unroll
      for (int c3 = 0; c3 < 3; c3++)
        kk[c3].u = *reinterpret_cast<const uint4*>(Kp1 + (t + c3 * 256) * 8);
    }

    #pragma unroll
    for (int s = 0; s < 2; s++) {
      const int pc = ((s * 4 + q) ^ (m16 & 7)) * 8;
      short8 bfr[3], af0[3], af1[3];
      #pragma unroll
      for (int cc = 0; cc < 3; cc++)
        bfr[cc] = *reinterpret_cast<const short8*>(
            &Vs[(wc * 48 + cc * 16 + m16) * 64 + pc]);
      #pragma unroll
      for (int a = 0; a < 3; a++) {
        af0[a] = *reinterpret_cast<const short8*>(
            &Ks0[(wr * 48 + a * 16 + m16) * 64 + pc]);
        af1[a] = *reinterpret_cast<const short8*>(
            &Ks1[(wr * 48 + a * 16 + m16) * 64 + pc]);
      }
      #pragma unroll
      for (int a = 0; a < 3; a++)
        #pragma unroll
        for (int cc = 0; cc < 3; cc++) {
          acc[0][a][cc] = __builtin_amdgcn_mfma_f32_16x16x32_bf16(
              af0[a], bfr[cc], acc[0][a][cc], 0, 0, 0);
          acc[1][a][cc] = __builtin_amdgcn_mfma_f32_16x16x32_bf16(
              af1[a], bfr[cc], acc[1][a][cc], 0, 0, 0);
        }
    }
  }

  // epilogue: assemble rows in LDS, then coalesced 16B global stores
  __syncthreads();
  #pragma unroll
  for (int isel = 0; isel < 2; isel++)
    #pragma unroll
    for (int a = 0; a < 3; a++)
      #pragma unroll
      for (int cc = 0; cc < 3; cc++) {
        const int j0 = wr * 48 + a * 16, k0c = wc * 48 + cc * 16;
        #pragma unroll
        for (int r = 0; r < 4; r++)
          smem[isel * 9216 + (j0 + q * 4 + r) * 96 + k0c + m16] =
              __float2bfloat16(acc[isel][a][cc][r]);
      }
  __syncthreads();
  const size_t obase = (size_t)(b * 96 + i0) * 9216;
  #pragma unroll
  for (int c = t; c < 2304; c += 256)
    *reinterpret_cast<uint4*>(FULL + obase + c * 8) =
        *reinterpret_cast<const uint4*>(&smem[c * 8]);
}

// ------- stage C: 128x64, BK=64, split-K=4, 1-barrier double-buffer ---------
// LDS rows: 64 bf16 = 128 B = 8 chunks; phys chunk = logical ^ (row & 7)
// Async staging for step k+1 issued BEFORE compute of step k; single
// __syncthreads per step drains loads that had a full compute phase to land.
__global__ __launch_bounds__(256) void stage_c_mfma(
    const bf16* __restrict__ FULL, const bf16* __restrict__ WoT,
    float* __restrict__ out) {
  const int bm = blockIdx.x * 128, bn = blockIdx.y * 64;
  const int kbase = blockIdx.z * 2304;
  __shared__ __align__(16) bf16 As[2][128 * 64];   // 16 KB each
  __shared__ __align__(16) bf16 Bs[2][64 * 64];    //  8 KB each  (48 KB total)
  const int t = threadIdx.x;
  const int w = t >> 6, lane = t & 63;
  const int m16 = lane & 15, q = lane >> 4;
  const int l8 = lane >> 3, l7 = lane & 7;

  v4f acc[2][4] = {};

#define SC_STAGE(buf, k0)                                                    \
  {                                                                          \
    _Pragma("unroll")                                                        \
    for (int c = 0; c < 4; c++) {                                            \
      const int r0 = (w * 4 + c) * 8;                                        \
      async_cp16(&As[buf][(w * 4 + c) * 512],                                \
                 FULL + (size_t)(bm + r0 + l8) * 9216 + (k0) + (l7 ^ l8) * 8); \
    }                                                                        \
    _Pragma("unroll")                                                        \
    for (int c = 0; c < 2; c++) {                                            \
      const int r0 = (w * 2 + c) * 8;                                        \
      async_cp16(&Bs[buf][(w * 2 + c) * 512],                                \
                 WoT + (size_t)(bn + r0 + l8) * 9216 + (k0) + (l7 ^ l8) * 8);  \
    }                                                                        \
  }

#define SC_COMPUTE(buf)                                                      \
  {                                                                          \
    _Pragma("unroll")                                                        \
    for (int s = 0; s < 2; s++) {                                            \
      const int pc = ((s * 4 + q) ^ (m16 & 7)) * 8;                          \
      short8 af[2], bfr[4];                                                  \
      _Pragma("unroll")                                                      \
      for (int mt = 0; mt < 2; mt++)                                         \
        af[mt] = *reinterpret_cast<const short8*>(                           \
            &As[buf][(w * 32 + mt * 16 + m16) * 64 + pc]);                   \
      _Pragma("unroll")                                                      \
      for (int nt = 0; nt < 4; nt++)                                         \
        bfr[nt] = *reinterpret_cast<const short8*>(                          \
            &Bs[buf][(nt * 16 + m16) * 64 + pc]);                            \
      _Pragma("unroll")                                                      \
      for (int mt = 0; mt < 2; mt++)                                         \
        _Pragma("unroll")                                                    \
        for (int nt = 0; nt < 4; nt++)                                       \
          acc[mt][nt] = __builtin_amdgcn_mfma_f32_16x16x32_bf16(             \
              af[mt], bfr[nt], acc[mt][nt], 0, 0, 0);                        \
    }                                                                        \
  }

  SC_STAGE(0, kbase);                 // prologue: step 0 into buf 0
  __syncthreads();

  for (int it = 0; it < 18; it++) {   // steps 2it (buf0) and 2it+1 (buf1)
    SC_STAGE(1, kbase + (2 * it + 1) * 64);
    SC_COMPUTE(0);
    __syncthreads();
    if (it < 17) SC_STAGE(0, kbase + (2 * it + 2) * 64);
    SC_COMPUTE(1);
    __syncthreads();
  }

  #pragma unroll
  for (int mt = 0; mt < 2; mt++)
    #pragma unroll
    for (int nt = 0; nt < 4; nt++)
      #pragma unroll
      for (int r = 0; r < 4; r++) {
        const int row = bm + w * 32 + mt * 16 + q * 4 + r;
        const int col = bn + nt * 16 + m16;
        atomicAdd(&out[(size_t)row * 512 + col], acc[mt][nt][r]);
      }
#undef SC_STAGE
#undef SC_COMPUTE
}

extern "C" void kernel_launch(void* const* d_in, const int* in_sizes, int n_in,
                              void* d_out, int out_size, void* d_ws, size_t ws_size,
                              hipStream_t stream) {
  const float* queries = (const float*)d_in[0];
  const float* keys    = (const float*)d_in[1];
  const float* values  = (const float*)d_in[2];
  // d_in[3] = attn_mask (unused by reference)
  const float* Wq   = (const float*)d_in[4];
  const float* bq   = (const float*)d_in[5];
  const float* Wk   = (const float*)d_in[6];
  const float* bk   = (const float*)d_in[7];
  const float* Wv   = (const float*)d_in[8];
  const float* bv   = (const float*)d_in[9];
  const float* core = (const float*)d_in[10];
  const float* Wo   = (const float*)d_in[11];
  const float* bo   = (const float*)d_in[12];
  float* out = (float*)d_out;

  char* ws = (char*)d_ws;
  bf16* AQb = (bf16*)(ws);                   // 3.15 MB (3072*512) = core*q/8
  bf16* KPb = (bf16*)(ws + 3145728);         // 3.15 MB
  bf16* VPb = (bf16*)(ws + 6291456);         // 3.15 MB
  bf16* WTq = (bf16*)(ws + 9437184);         // 0.52 MB (512*512)
  bf16* WTk = (bf16*)(ws + 9961472);         // 0.52 MB
  bf16* WTv = (bf16*)(ws + 10485760);        // 0.52 MB
  bf16* WoT = (bf16*)(ws + 11010048);        // 9.44 MB (512*9216)
  bf16* FULL = (bf16*)(ws + 20447232);       // 56.62 MB (3072*9216)
  // Xb* overlay the FULL region: proj reads them before stage_b writes FULL.
  bf16* Xbq = FULL;
  bf16* Xbk = FULL + 1572864;
  bf16* Xbv = FULL + 3145728;

  prep<<<dim3(8064), dim3(256), 0, stream>>>(
      Wo, Wq, Wk, Wv, queries, keys, values, bo,
      WoT, WTq, WTk, WTv, Xbq, Xbk, Xbv, out);

  proj_mfma<<<dim3(24, 8, 3), dim3(256), 0, stream>>>(
      Xbq, Xbk, Xbv, WTq, WTk, WTv, bq, bk, bv, core, AQb, KPb, VPb);

  stage_b_mfma<<<dim3(48, 32), dim3(256), 0, stream>>>(AQb, KPb, VPb, FULL);

  stage_c_mfma<<<dim3(24, 8, 4), dim3(256), 0, stream>>>(FULL, WoT, out);
}

// Round 14
// 201.912 us; speedup vs baseline: 1.1720x; 1.0035x over previous
//
#include <hip/hip_runtime.h>
#include <hip/hip_bf16.h>
#include <stdint.h>

using bf16 = __hip_bfloat16;
typedef float v4f __attribute__((ext_vector_type(4)));
typedef short short8 __attribute__((ext_vector_type(8)));

// Shapes (fixed): B=32, L=S=96, D=512, H=8, DH=64, d_ff=9216. M = B*L = 3072.

// ---- async global->LDS 16B (wave-uniform LDS base + lane*16) ---------------
__device__ __forceinline__ void async_cp16(void* l, const void* g) {
  __builtin_amdgcn_global_load_lds(
      (const __attribute__((address_space(1))) void*)(uintptr_t)g,
      (__attribute__((address_space(3))) void*)(uintptr_t)l, 16, 0, 0);
}

// ---- prep: transposes (64x32 tiles, 16B stores) + X cvt + out init ---------
// bids: [0,2304) Wo; [2304,2688) Wq/Wk/Wv; [2688,3840) X cvt; [3840,5376) out.
__global__ __launch_bounds__(256) void prep(
    const float* __restrict__ Wo, const float* __restrict__ Wq,
    const float* __restrict__ Wk, const float* __restrict__ Wv,
    const float* __restrict__ Xq, const float* __restrict__ Xk,
    const float* __restrict__ Xv, const float* __restrict__ bo,
    bf16* __restrict__ WoT, bf16* __restrict__ WTq,
    bf16* __restrict__ WTk, bf16* __restrict__ WTv,
    bf16* __restrict__ Xbq, bf16* __restrict__ Xbk, bf16* __restrict__ Xbv,
    float* __restrict__ out) {
  const int bid = blockIdx.x, t = threadIdx.x;
  if (bid < 2688) {                       // transpose f32 -> bf16, 64k x 32n
    __shared__ bf16 T[32][80];            // row = 160 B (16B-aligned)
    const float* src; bf16* dst; int K, N, kx, ny;
    if (bid < 2304) {                     // Wo: 144 x 16 tiles
      src = Wo; dst = WoT; K = 9216; N = 512; kx = bid % 144; ny = bid / 144;
    } else {
      const int r = bid - 2304, which = r >> 7, rr = r & 127;
      kx = rr & 7; ny = rr >> 3; K = 512; N = 512;
      src = which == 0 ? Wq : (which == 1 ? Wk : Wv);
      dst = which == 0 ? WTq : (which == 1 ? WTk : WTv);
    }
    const int k0 = kx * 64, n0 = ny * 32;
    const int kr = t >> 2, nc = (t & 3) * 8;
    float4 v0 = *reinterpret_cast<const float4*>(src + (size_t)(k0 + kr) * N + n0 + nc);
    float4 v1 = *reinterpret_cast<const float4*>(src + (size_t)(k0 + kr) * N + n0 + nc + 4);
    T[nc + 0][kr] = __float2bfloat16(v0.x); T[nc + 1][kr] = __float2bfloat16(v0.y);
    T[nc + 2][kr] = __float2bfloat16(v0.z); T[nc + 3][kr] = __float2bfloat16(v0.w);
    T[nc + 4][kr] = __float2bfloat16(v1.x); T[nc + 5][kr] = __float2bfloat16(v1.y);
    T[nc + 6][kr] = __float2bfloat16(v1.z); T[nc + 7][kr] = __float2bfloat16(v1.w);
    __syncthreads();
    const int n = t >> 3, kc = (t & 7) * 8;
    *reinterpret_cast<uint4*>(dst + (size_t)(n0 + n) * K + k0 + kc) =
        *reinterpret_cast<const uint4*>(&T[n][kc]);
  } else if (bid < 3840) {                // X f32 -> bf16 (16 elems/thread)
    const int r = bid - 2688;
    const int which = r / 384, blk = r % 384;
    const float* src = which == 0 ? Xq : (which == 1 ? Xk : Xv);
    bf16* dst = which == 0 ? Xbq : (which == 1 ? Xbk : Xbv);
    const int base = blk * 4096 + t * 16;
    float4 a = *reinterpret_cast<const float4*>(src + base);
    float4 b = *reinterpret_cast<const float4*>(src + base + 4);
    float4 c = *reinterpret_cast<const float4*>(src + base + 8);
    float4 d = *reinterpret_cast<const float4*>(src + base + 12);
    union { uint4 u; bf16 h[8]; } o1, o2;
    o1.h[0] = __float2bfloat16(a.x); o1.h[1] = __float2bfloat16(a.y);
    o1.h[2] = __float2bfloat16(a.z); o1.h[3] = __float2bfloat16(a.w);
    o1.h[4] = __float2bfloat16(b.x); o1.h[5] = __float2bfloat16(b.y);
    o1.h[6] = __float2bfloat16(b.z); o1.h[7] = __float2bfloat16(b.w);
    o2.h[0] = __float2bfloat16(c.x); o2.h[1] = __float2bfloat16(c.y);
    o2.h[2] = __float2bfloat16(c.z); o2.h[3] = __float2bfloat16(c.w);
    o2.h[4] = __float2bfloat16(d.x); o2.h[5] = __float2bfloat16(d.y);
    o2.h[6] = __float2bfloat16(d.z); o2.h[7] = __float2bfloat16(d.w);
    *reinterpret_cast<uint4*>(dst + base) = o1.u;
    *reinterpret_cast<uint4*>(dst + base + 8) = o2.u;
  } else {                                // init out with bias
    const int r = bid - 3840;
    const int idx = (r * 256 + t) * 4;    // < 3072*512
    *reinterpret_cast<float4*>(out + idx) =
        *reinterpret_cast<const float4*>(bo + (idx & 511));
  }
}

// ---- fused Q/K/V projections: 64x64, 2 waves, BK=64 double-buffered --------
// z==0 folds core[n,h]/8 into the output (raw-reshape: n=row/384, h=col&63).
// LDS rows: 64 bf16 = 8 chunks; phys chunk = logical ^ (row & 7)
__global__ __launch_bounds__(128) void proj_mfma(
    const bf16* __restrict__ Xb0, const bf16* __restrict__ Xb1,
    const bf16* __restrict__ Xb2,
    const bf16* __restrict__ WT0, const bf16* __restrict__ WT1,
    const bf16* __restrict__ WT2,
    const float* __restrict__ b0, const float* __restrict__ b1,
    const float* __restrict__ b2, const float* __restrict__ core,
    bf16* __restrict__ O0, bf16* __restrict__ O1, bf16* __restrict__ O2) {
  const int z = blockIdx.z;
  const bf16* X    = z == 0 ? Xb0 : (z == 1 ? Xb1 : Xb2);
  const bf16* WT   = z == 0 ? WT0 : (z == 1 ? WT1 : WT2);
  const float* bia = z == 0 ? b0 : (z == 1 ? b1 : b2);
  bf16* O          = z == 0 ? O0 : (z == 1 ? O1 : O2);

  const int bm = blockIdx.x * 64, bn = blockIdx.y * 64;
  __shared__ __align__(16) bf16 As[2][64 * 64];   // 8 KB each
  __shared__ __align__(16) bf16 Bs[2][64 * 64];   // 8 KB each (32 KB total)
  const int t = threadIdx.x;
  const int w = t >> 6, lane = t & 63;
  const int m16 = lane & 15, q = lane >> 4;
  const int l8 = lane >> 3, l7 = lane & 7;

  v4f acc[2][4] = {};

#define PJ_STAGE(buf, k0)                                                    \
  {                                                                          \
    _Pragma("unroll")                                                        \
    for (int c = 0; c < 4; c++) {                                            \
      const int r0 = (w * 4 + c) * 8;                                        \
      async_cp16(&As[buf][(w * 4 + c) * 512],                                \
                 X + (size_t)(bm + r0 + l8) * 512 + (k0) + (l7 ^ l8) * 8);   \
      async_cp16(&Bs[buf][(w * 4 + c) * 512],                                \
                 WT + (size_t)(bn + r0 + l8) * 512 + (k0) + (l7 ^ l8) * 8);  \
    }                                                                        \
  }

#define PJ_COMPUTE(buf)                                                      \
  {                                                                          \
    _Pragma("unroll")                                                        \
    for (int s = 0; s < 2; s++) {                                            \
      const int pc = ((s * 4 + q) ^ (m16 & 7)) * 8;                          \
      short8 af[2], bfr[4];                                                  \
      _Pragma("unroll")                                                      \
      for (int mt = 0; mt < 2; mt++)                                         \
        af[mt] = *reinterpret_cast<const short8*>(                           \
            &As[buf][(w * 32 + mt * 16 + m16) * 64 + pc]);                   \
      _Pragma("unroll")                                                      \
      for (int nt = 0; nt < 4; nt++)                                         \
        bfr[nt] = *reinterpret_cast<const short8*>(                          \
            &Bs[buf][(nt * 16 + m16) * 64 + pc]);                            \
      _Pragma("unroll")                                                      \
      for (int mt = 0; mt < 2; mt++)                                         \
        _Pragma("unroll")                                                    \
        for (int nt = 0; nt < 4; nt++)                                       \
          acc[mt][nt] = __builtin_amdgcn_mfma_f32_16x16x32_bf16(             \
              af[mt], bfr[nt], acc[mt][nt], 0, 0, 0);                        \
    }                                                                        \
  }

  PJ_STAGE(0, 0);
  __syncthreads();
  for (int it = 0; it < 4; it++) {      // 8 K-steps of 64
    PJ_STAGE(1, (2 * it + 1) * 64);
    PJ_COMPUTE(0);
    __syncthreads();
    if (it < 3) PJ_STAGE(0, (2 * it + 2) * 64);
    PJ_COMPUTE(1);
    __syncthreads();
  }
#undef PJ_STAGE
#undef PJ_COMPUTE

  const bool isQ = (z == 0);
  const int nblk = bm / 384;            // 64 | 384 → block-uniform head index
  #pragma unroll
  for (int mt = 0; mt < 2; mt++)
    #pragma unroll
    for (int nt = 0; nt < 4; nt++)
      #pragma unroll
      for (int r = 0; r < 4; r++) {
        const int row = bm + w * 32 + mt * 16 + q * 4 + r;
        const int col = bn + nt * 16 + m16;
        float v = acc[mt][nt][r] + bia[col];
        if (isQ) v *= core[nblk * 64 + (col & 63)] * 0.125f;
        O[(size_t)row * 512 + col] = __float2bfloat16(v);
      }
}

// ------------- stage B (R6/R9/R10 proven: MFMA, TI=2, async V, swizzled) ----
// raw-reshape indexing: aq/k/v[n,b,i,h] = P[n*196608 + b*6144 + i*64 + h]
// LDS rows: 64 bf16 = 128 B, phys chunk = logical chunk ^ (row & 7)
__global__ __launch_bounds__(256) void stage_b_mfma(
    const bf16* __restrict__ AQ, const bf16* __restrict__ KPb,
    const bf16* __restrict__ VPb, bf16* __restrict__ FULL) {
  const int b = blockIdx.y;
  const int i0 = blockIdx.x * 2;

  __shared__ __align__(16) bf16 smem[19456];  // Ks0|Ks1|Vs|aq2 ; epi: 2x9216
  bf16* Ks0 = smem;            // 6144 (96x64 swizzled)
  bf16* Ks1 = smem + 6144;
  bf16* Vs  = smem + 12288;
  bf16* aqs = smem + 18432;    // 2 x 512

  const int t = threadIdx.x;
  const int w = t >> 6, lane = t & 63;
  const int wr = w >> 1, wc = w & 1;    // 2x2 waves, each 48x48 region
  const int m16 = lane & 15, q = lane >> 4;
  const int l8 = lane >> 3, l7 = lane & 7;

  if (t < 128) {                         // load aq rows for both i
    const int isel = t & 1, n = t >> 4, seg = (t >> 1) & 7;
    *reinterpret_cast<uint4*>(&aqs[isel * 512 + n * 64 + seg * 8]) =
        *reinterpret_cast<const uint4*>(
            AQ + (size_t)n * 196608 + b * 6144 + (i0 + isel) * 64 + seg * 8);
  }

  union U8 { uint4 u; bf16 h[8]; };
  const int colq = (t & 7) * 8;          // k-column of this thread's K chunks
  const int rowk = t >> 3;               // base K row (+32 per chunk iter)
  const int krow7 = rowk & 7;

  U8 kk[3];
  {
    const bf16* Kp = KPb + b * 6144;     // n = 0 slab
    #pragma unroll
    for (int c3 = 0; c3 < 3; c3++)
      kk[c3].u = *reinterpret_cast<const uint4*>(Kp + (t + c3 * 256) * 8);
  }

  v4f acc[2][3][3] = {};

  for (int n = 0; n < 8; n++) {
    __syncthreads();                     // prev frag reads done; aqs ready
    // async V staging (swizzled): 3 calls/wave, 8 rows each
    const bf16* Vp = VPb + (size_t)n * 196608 + b * 6144;
    #pragma unroll
    for (int c = 0; c < 3; c++) {
      const int r0 = (w * 3 + c) * 8;
      async_cp16(&Vs[(w * 3 + c) * 512],
                 Vp + (r0 + l8) * 64 + (l7 ^ l8) * 8);
    }
    // aq scales for this n (f32, hoisted)
    float a0f[8], a1f[8];
    {
      U8 a0, a1;
      a0.u = *reinterpret_cast<const uint4*>(&aqs[n * 64 + colq]);
      a1.u = *reinterpret_cast<const uint4*>(&aqs[512 + n * 64 + colq]);
      #pragma unroll
      for (int e = 0; e < 8; e++) {
        a0f[e] = __bfloat162float(a0.h[e]);
        a1f[e] = __bfloat162float(a1.h[e]);
      }
    }
    // repack K with per-i scales into swizzled LDS
    #pragma unroll
    for (int c3 = 0; c3 < 3; c3++) {
      U8 s0, s1;
      #pragma unroll
      for (int e = 0; e < 8; e++) {
        const float kv = __bfloat162float(kk[c3].h[e]);
        s0.h[e] = __float2bfloat16(kv * a0f[e]);
        s1.h[e] = __float2bfloat16(kv * a1f[e]);
      }
      const int phys = (rowk + 32 * c3) * 64 + (l7 ^ krow7) * 8;
      *reinterpret_cast<uint4*>(&Ks0[phys]) = s0.u;
      *reinterpret_cast<uint4*>(&Ks1[phys]) = s1.u;
    }
    __syncthreads();                     // drains async V + K writes
    // prefetch next n's K slab (latency hides behind MFMAs)
    if (n < 7) {
      const bf16* Kp1 = KPb + (size_t)(n + 1) * 196608 + b * 6144;
      #pragma unroll
      for (int c3 = 0; c3 < 3; c3++)
        kk[c3].u = *reinterpret_cast<const uint4*>(Kp1 + (t + c3 * 256) * 8);
    }

    #pragma unroll
    for (int s = 0; s < 2; s++) {
      const int pc = ((s * 4 + q) ^ (m16 & 7)) * 8;
      short8 bfr[3], af0[3], af1[3];
      #pragma unroll
      for (int cc = 0; cc < 3; cc++)
        bfr[cc] = *reinterpret_cast<const short8*>(
            &Vs[(wc * 48 + cc * 16 + m16) * 64 + pc]);
      #pragma unroll
      for (int a = 0; a < 3; a++) {
        af0[a] = *reinterpret_cast<const short8*>(
            &Ks0[(wr * 48 + a * 16 + m16) * 64 + pc]);
        af1[a] = *reinterpret_cast<const short8*>(
            &Ks1[(wr * 48 + a * 16 + m16) * 64 + pc]);
      }
      #pragma unroll
      for (int a = 0; a < 3; a++)
        #pragma unroll
        for (int cc = 0; cc < 3; cc++) {
          acc[0][a][cc] = __builtin_amdgcn_mfma_f32_16x16x32_bf16(
              af0[a], bfr[cc], acc[0][a][cc], 0, 0, 0);
          acc[1][a][cc] = __builtin_amdgcn_mfma_f32_16x16x32_bf16(
              af1[a], bfr[cc], acc[1][a][cc], 0, 0, 0);
        }
    }
  }

  // epilogue: assemble rows in LDS, then coalesced 16B global stores
  __syncthreads();
  #pragma unroll
  for (int isel = 0; isel < 2; isel++)
    #pragma unroll
    for (int a = 0; a < 3; a++)
      #pragma unroll
      for (int cc = 0; cc < 3; cc++) {
        const int j0 = wr * 48 + a * 16, k0c = wc * 48 + cc * 16;
        #pragma unroll
        for (int r = 0; r < 4; r++)
          smem[isel * 9216 + (j0 + q * 4 + r) * 96 + k0c + m16] =
              __float2bfloat16(acc[isel][a][cc][r]);
      }
  __syncthreads();
  const size_t obase = (size_t)(b * 96 + i0) * 9216;
  #pragma unroll
  for (int c = t; c < 2304; c += 256)
    *reinterpret_cast<uint4*>(FULL + obase + c * 8) =
        *reinterpret_cast<const uint4*>(&smem[c * 8]);
}

// ------- stage C (R12 proven): 128x64, BK=64, split-K=4, 1-barrier dbuf -----
// LDS rows: 64 bf16 = 128 B = 8 chunks; phys chunk = logical ^ (row & 7)
__global__ __launch_bounds__(256) void stage_c_mfma(
    const bf16* __restrict__ FULL, const bf16* __restrict__ WoT,
    float* __restrict__ out) {
  const int bm = blockIdx.x * 128, bn = blockIdx.y * 64;
  const int kbase = blockIdx.z * 2304;
  __shared__ __align__(16) bf16 As[2][128 * 64];   // 16 KB each
  __shared__ __align__(16) bf16 Bs[2][64 * 64];    //  8 KB each  (48 KB total)
  const int t = threadIdx.x;
  const int w = t >> 6, lane = t & 63;
  const int m16 = lane & 15, q = lane >> 4;
  const int l8 = lane >> 3, l7 = lane & 7;

  v4f acc[2][4] = {};

#define SC_STAGE(buf, k0)                                                    \
  {                                                                          \
    _Pragma("unroll")                                                        \
    for (int c = 0; c < 4; c++) {                                            \
      const int r0 = (w * 4 + c) * 8;                                        \
      async_cp16(&As[buf][(w * 4 + c) * 512],                                \
                 FULL + (size_t)(bm + r0 + l8) * 9216 + (k0) + (l7 ^ l8) * 8); \
    }                                                                        \
    _Pragma("unroll")                                                        \
    for (int c = 0; c < 2; c++) {                                            \
      const int r0 = (w * 2 + c) * 8;                                        \
      async_cp16(&Bs[buf][(w * 2 + c) * 512],                                \
                 WoT + (size_t)(bn + r0 + l8) * 9216 + (k0) + (l7 ^ l8) * 8);  \
    }                                                                        \
  }

#define SC_COMPUTE(buf)                                                      \
  {                                                                          \
    _Pragma("unroll")                                                        \
    for (int s = 0; s < 2; s++) {                                            \
      const int pc = ((s * 4 + q) ^ (m16 & 7)) * 8;                          \
      short8 af[2], bfr[4];                                                  \
      _Pragma("unroll")                                                      \
      for (int mt = 0; mt < 2; mt++)                                         \
        af[mt] = *reinterpret_cast<const short8*>(                           \
            &As[buf][(w * 32 + mt * 16 + m16) * 64 + pc]);                   \
      _Pragma("unroll")                                                      \
      for (int nt = 0; nt < 4; nt++)                                         \
        bfr[nt] = *reinterpret_cast<const short8*>(                          \
            &Bs[buf][(nt * 16 + m16) * 64 + pc]);                            \
      _Pragma("unroll")                                                      \
      for (int mt = 0; mt < 2; mt++)                                         \
        _Pragma("unroll")                                                    \
        for (int nt = 0; nt < 4; nt++)                                       \
          acc[mt][nt] = __builtin_amdgcn_mfma_f32_16x16x32_bf16(             \
              af[mt], bfr[nt], acc[mt][nt], 0, 0, 0);                        \
    }                                                                        \
  }

  SC_STAGE(0, kbase);                 // prologue: step 0 into buf 0
  __syncthreads();

  for (int it = 0; it < 18; it++) {   // steps 2it (buf0) and 2it+1 (buf1)
    SC_STAGE(1, kbase + (2 * it + 1) * 64);
    SC_COMPUTE(0);
    __syncthreads();
    if (it < 17) SC_STAGE(0, kbase + (2 * it + 2) * 64);
    SC_COMPUTE(1);
    __syncthreads();
  }

  #pragma unroll
  for (int mt = 0; mt < 2; mt++)
    #pragma unroll
    for (int nt = 0; nt < 4; nt++)
      #pragma unroll
      for (int r = 0; r < 4; r++) {
        const int row = bm + w * 32 + mt * 16 + q * 4 + r;
        const int col = bn + nt * 16 + m16;
        atomicAdd(&out[(size_t)row * 512 + col], acc[mt][nt][r]);
      }
#undef SC_STAGE
#undef SC_COMPUTE
}

extern "C" void kernel_launch(void* const* d_in, const int* in_sizes, int n_in,
                              void* d_out, int out_size, void* d_ws, size_t ws_size,
                              hipStream_t stream) {
  const float* queries = (const float*)d_in[0];
  const float* keys    = (const float*)d_in[1];
  const float* values  = (const float*)d_in[2];
  // d_in[3] = attn_mask (unused by reference)
  const float* Wq   = (const float*)d_in[4];
  const float* bq   = (const float*)d_in[5];
  const float* Wk   = (const float*)d_in[6];
  const float* bk   = (const float*)d_in[7];
  const float* Wv   = (const float*)d_in[8];
  const float* bv   = (const float*)d_in[9];
  const float* core = (const float*)d_in[10];
  const float* Wo   = (const float*)d_in[11];
  const float* bo   = (const float*)d_in[12];
  float* out = (float*)d_out;

  char* ws = (char*)d_ws;
  bf16* AQb = (bf16*)(ws);                   // 3.15 MB (3072*512) = core*q/8
  bf16* KPb = (bf16*)(ws + 3145728);         // 3.15 MB
  bf16* VPb = (bf16*)(ws + 6291456);         // 3.15 MB
  bf16* WTq = (bf16*)(ws + 9437184);         // 0.52 MB (512*512)
  bf16* WTk = (bf16*)(ws + 9961472);         // 0.52 MB
  bf16* WTv = (bf16*)(ws + 10485760);        // 0.52 MB
  bf16* WoT = (bf16*)(ws + 11010048);        // 9.44 MB (512*9216)
  bf16* FULL = (bf16*)(ws + 20447232);       // 56.62 MB (3072*9216)
  // Xb* overlay the FULL region: proj reads them before stage_b writes FULL.
  bf16* Xbq = FULL;
  bf16* Xbk = FULL + 1572864;
  bf16* Xbv = FULL + 3145728;

  prep<<<dim3(5376), dim3(256), 0, stream>>>(
      Wo, Wq, Wk, Wv, queries, keys, values, bo,
      WoT, WTq, WTk, WTv, Xbq, Xbk, Xbv, out);

  proj_mfma<<<dim3(48, 8, 3), dim3(128), 0, stream>>>(
      Xbq, Xbk, Xbv, WTq, WTk, WTv, bq, bk, bv, core, AQb, KPb, VPb);

  stage_b_mfma<<<dim3(48, 32), dim3(256), 0, stream>>>(AQb, KPb, VPb, FULL);

  stage_c_mfma<<<dim3(24, 8, 4), dim3(256), 0, stream>>>(FULL, WoT, out);
}

// Round 15
// 198.308 us; speedup vs baseline: 1.1933x; 1.0182x over previous
//
#include <hip/hip_runtime.h>
#include <hip/hip_bf16.h>
#include <stdint.h>

using bf16 = __hip_bfloat16;
typedef float v4f __attribute__((ext_vector_type(4)));
typedef short short8 __attribute__((ext_vector_type(8)));

// Shapes (fixed): B=32, L=S=96, D=512, H=8, DH=64, d_ff=9216. M = B*L = 3072.

// ---- async global->LDS 16B (wave-uniform LDS base + lane*16) ---------------
__device__ __forceinline__ void async_cp16(void* l, const void* g) {
  __builtin_amdgcn_global_load_lds(
      (const __attribute__((address_space(1))) void*)(uintptr_t)g,
      (__attribute__((address_space(3))) void*)(uintptr_t)l, 16, 0, 0);
}

// ---- prep: transposes (64x32 tiles, 16B stores) + X cvt + out init ---------
// bids: [0,2304) Wo; [2304,2688) Wq/Wk/Wv; [2688,3840) X cvt; [3840,5376) out.
__global__ __launch_bounds__(256) void prep(
    const float* __restrict__ Wo, const float* __restrict__ Wq,
    const float* __restrict__ Wk, const float* __restrict__ Wv,
    const float* __restrict__ Xq, const float* __restrict__ Xk,
    const float* __restrict__ Xv, const float* __restrict__ bo,
    bf16* __restrict__ WoT, bf16* __restrict__ WTq,
    bf16* __restrict__ WTk, bf16* __restrict__ WTv,
    bf16* __restrict__ Xbq, bf16* __restrict__ Xbk, bf16* __restrict__ Xbv,
    float* __restrict__ out) {
  const int bid = blockIdx.x, t = threadIdx.x;
  if (bid < 2688) {                       // transpose f32 -> bf16, 64k x 32n
    __shared__ bf16 T[32][80];            // row = 160 B (16B-aligned)
    const float* src; bf16* dst; int K, N, kx, ny;
    if (bid < 2304) {                     // Wo: 144 x 16 tiles
      src = Wo; dst = WoT; K = 9216; N = 512; kx = bid % 144; ny = bid / 144;
    } else {
      const int r = bid - 2304, which = r >> 7, rr = r & 127;
      kx = rr & 7; ny = rr >> 3; K = 512; N = 512;
      src = which == 0 ? Wq : (which == 1 ? Wk : Wv);
      dst = which == 0 ? WTq : (which == 1 ? WTk : WTv);
    }
    const int k0 = kx * 64, n0 = ny * 32;
    const int kr = t >> 2, nc = (t & 3) * 8;
    float4 v0 = *reinterpret_cast<const float4*>(src + (size_t)(k0 + kr) * N + n0 + nc);
    float4 v1 = *reinterpret_cast<const float4*>(src + (size_t)(k0 + kr) * N + n0 + nc + 4);
    T[nc + 0][kr] = __float2bfloat16(v0.x); T[nc + 1][kr] = __float2bfloat16(v0.y);
    T[nc + 2][kr] = __float2bfloat16(v0.z); T[nc + 3][kr] = __float2bfloat16(v0.w);
    T[nc + 4][kr] = __float2bfloat16(v1.x); T[nc + 5][kr] = __float2bfloat16(v1.y);
    T[nc + 6][kr] = __float2bfloat16(v1.z); T[nc + 7][kr] = __float2bfloat16(v1.w);
    __syncthreads();
    const int n = t >> 3, kc = (t & 7) * 8;
    *reinterpret_cast<uint4*>(dst + (size_t)(n0 + n) * K + k0 + kc) =
        *reinterpret_cast<const uint4*>(&T[n][kc]);
  } else if (bid < 3840) {                // X f32 -> bf16 (16 elems/thread)
    const int r = bid - 2688;
    const int which = r / 384, blk = r % 384;
    const float* src = which == 0 ? Xq : (which == 1 ? Xk : Xv);
    bf16* dst = which == 0 ? Xbq : (which == 1 ? Xbk : Xbv);
    const int base = blk * 4096 + t * 16;
    float4 a = *reinterpret_cast<const float4*>(src + base);
    float4 b = *reinterpret_cast<const float4*>(src + base + 4);
    float4 c = *reinterpret_cast<const float4*>(src + base + 8);
    float4 d = *reinterpret_cast<const float4*>(src + base + 12);
    union { uint4 u; bf16 h[8]; } o1, o2;
    o1.h[0] = __float2bfloat16(a.x); o1.h[1] = __float2bfloat16(a.y);
    o1.h[2] = __float2bfloat16(a.z); o1.h[3] = __float2bfloat16(a.w);
    o1.h[4] = __float2bfloat16(b.x); o1.h[5] = __float2bfloat16(b.y);
    o1.h[6] = __float2bfloat16(b.z); o1.h[7] = __float2bfloat16(b.w);
    o2.h[0] = __float2bfloat16(c.x); o2.h[1] = __float2bfloat16(c.y);
    o2.h[2] = __float2bfloat16(c.z); o2.h[3] = __float2bfloat16(c.w);
    o2.h[4] = __float2bfloat16(d.x); o2.h[5] = __float2bfloat16(d.y);
    o2.h[6] = __float2bfloat16(d.z); o2.h[7] = __float2bfloat16(d.w);
    *reinterpret_cast<uint4*>(dst + base) = o1.u;
    *reinterpret_cast<uint4*>(dst + base + 8) = o2.u;
  } else {                                // init out with bias
    const int r = bid - 3840;
    const int idx = (r * 256 + t) * 4;    // < 3072*512
    *reinterpret_cast<float4*>(out + idx) =
        *reinterpret_cast<const float4*>(bo + (idx & 511));
  }
}

// ---- fused Q/K/V projections: 64x64, 2 waves, BK=64 double-buffered --------
// z==0 folds core[n,h]/8 into the output (raw-reshape: n=row/384, h=col&63).
// LDS rows: 64 bf16 = 8 chunks; phys chunk = logical ^ (row & 7)
__global__ __launch_bounds__(128) void proj_mfma(
    const bf16* __restrict__ Xb0, const bf16* __restrict__ Xb1,
    const bf16* __restrict__ Xb2,
    const bf16* __restrict__ WT0, const bf16* __restrict__ WT1,
    const bf16* __restrict__ WT2,
    const float* __restrict__ b0, const float* __restrict__ b1,
    const float* __restrict__ b2, const float* __restrict__ core,
    bf16* __restrict__ O0, bf16* __restrict__ O1, bf16* __restrict__ O2) {
  const int z = blockIdx.z;
  const bf16* X    = z == 0 ? Xb0 : (z == 1 ? Xb1 : Xb2);
  const bf16* WT   = z == 0 ? WT0 : (z == 1 ? WT1 : WT2);
  const float* bia = z == 0 ? b0 : (z == 1 ? b1 : b2);
  bf16* O          = z == 0 ? O0 : (z == 1 ? O1 : O2);

  const int bm = blockIdx.x * 64, bn = blockIdx.y * 64;
  __shared__ __align__(16) bf16 As[2][64 * 64];   // 8 KB each
  __shared__ __align__(16) bf16 Bs[2][64 * 64];   // 8 KB each (32 KB total)
  const int t = threadIdx.x;
  const int w = t >> 6, lane = t & 63;
  const int m16 = lane & 15, q = lane >> 4;
  const int l8 = lane >> 3, l7 = lane & 7;

  v4f acc[2][4] = {};

#define PJ_STAGE(buf, k0)                                                    \
  {                                                                          \
    _Pragma("unroll")                                                        \
    for (int c = 0; c < 4; c++) {                                            \
      const int r0 = (w * 4 + c) * 8;                                        \
      async_cp16(&As[buf][(w * 4 + c) * 512],                                \
                 X + (size_t)(bm + r0 + l8) * 512 + (k0) + (l7 ^ l8) * 8);   \
      async_cp16(&Bs[buf][(w * 4 + c) * 512],                                \
                 WT + (size_t)(bn + r0 + l8) * 512 + (k0) + (l7 ^ l8) * 8);  \
    }                                                                        \
  }

#define PJ_COMPUTE(buf)                                                      \
  {                                                                          \
    _Pragma("unroll")                                                        \
    for (int s = 0; s < 2; s++) {                                            \
      const int pc = ((s * 4 + q) ^ (m16 & 7)) * 8;                          \
      short8 af[2], bfr[4];                                                  \
      _Pragma("unroll")                                                      \
      for (int mt = 0; mt < 2; mt++)                                         \
        af[mt] = *reinterpret_cast<const short8*>(                           \
            &As[buf][(w * 32 + mt * 16 + m16) * 64 + pc]);                   \
      _Pragma("unroll")                                                      \
      for (int nt = 0; nt < 4; nt++)                                         \
        bfr[nt] = *reinterpret_cast<const short8*>(                          \
            &Bs[buf][(nt * 16 + m16) * 64 + pc]);                            \
      _Pragma("unroll")                                                      \
      for (int mt = 0; mt < 2; mt++)                                         \
        _Pragma("unroll")                                                    \
        for (int nt = 0; nt < 4; nt++)                                       \
          acc[mt][nt] = __builtin_amdgcn_mfma_f32_16x16x32_bf16(             \
              af[mt], bfr[nt], acc[mt][nt], 0, 0, 0);                        \
    }                                                                        \
  }

  PJ_STAGE(0, 0);
  __syncthreads();
  for (int it = 0; it < 4; it++) {      // 8 K-steps of 64
    PJ_STAGE(1, (2 * it + 1) * 64);
    PJ_COMPUTE(0);
    __syncthreads();
    if (it < 3) PJ_STAGE(0, (2 * it + 2) * 64);
    PJ_COMPUTE(1);
    __syncthreads();
  }
#undef PJ_STAGE
#undef PJ_COMPUTE

  const bool isQ = (z == 0);
  const int nblk = bm / 384;            // 64 | 384 → block-uniform head index
  #pragma unroll
  for (int mt = 0; mt < 2; mt++)
    #pragma unroll
    for (int nt = 0; nt < 4; nt++)
      #pragma unroll
      for (int r = 0; r < 4; r++) {
        const int row = bm + w * 32 + mt * 16 + q * 4 + r;
        const int col = bn + nt * 16 + m16;
        float v = acc[mt][nt][r] + bia[col];
        if (isQ) v *= core[nblk * 64 + (col & 63)] * 0.125f;
        O[(size_t)row * 512 + col] = __float2bfloat16(v);
      }
}

// ------------- stage B: MFMA, TI=2, V double-buffered pipeline --------------
// raw-reshape indexing: aq/k/v[n,b,i,h] = P[n*196608 + b*6144 + i*64 + h]
// LDS rows: 64 bf16 = 128 B, phys chunk = logical chunk ^ (row & 7)
// Pipeline: barrier A drains V(n) (issued a full MFMA-phase ago); repack K;
// barrier B drains only LDS writes; V(n+1) + kk(n+1) issued during MFMA(n).
__global__ __launch_bounds__(256) void stage_b_mfma(
    const bf16* __restrict__ AQ, const bf16* __restrict__ KPb,
    const bf16* __restrict__ VPb, bf16* __restrict__ FULL) {
  const int b = blockIdx.y;
  const int i0 = blockIdx.x * 2;

  __shared__ __align__(16) bf16 smem[25600];  // Ks0|Ks1|Vs[2]|aq2 ; epi 2x9216
  bf16* Ks0 = smem;            // 6144 (96x64 swizzled)
  bf16* Ks1 = smem + 6144;     // 6144
  // Vs[0] = smem+12288, Vs[1] = smem+18432 (6144 each)
  bf16* aqs = smem + 24576;    // 2 x 512

  const int t = threadIdx.x;
  const int w = t >> 6, lane = t & 63;
  const int wr = w >> 1, wc = w & 1;    // 2x2 waves, each 48x48 region
  const int m16 = lane & 15, q = lane >> 4;
  const int l8 = lane >> 3, l7 = lane & 7;

  if (t < 128) {                         // load aq rows for both i
    const int isel = t & 1, n = t >> 4, seg = (t >> 1) & 7;
    *reinterpret_cast<uint4*>(&aqs[isel * 512 + n * 64 + seg * 8]) =
        *reinterpret_cast<const uint4*>(
            AQ + (size_t)n * 196608 + b * 6144 + (i0 + isel) * 64 + seg * 8);
  }

  union U8 { uint4 u; bf16 h[8]; };
  const int colq = (t & 7) * 8;          // k-column of this thread's K chunks
  const int rowk = t >> 3;               // base K row (+32 per chunk iter)
  const int krow7 = rowk & 7;

  U8 kk[3];
  {                                      // prologue: V(0) async + kk(0)
    const bf16* Vp = VPb + b * 6144;
    #pragma unroll
    for (int c = 0; c < 3; c++)
      async_cp16(&smem[12288 + (w * 3 + c) * 512],
                 Vp + ((w * 3 + c) * 8 + l8) * 64 + (l7 ^ l8) * 8);
    const bf16* Kp = KPb + b * 6144;
    #pragma unroll
    for (int c3 = 0; c3 < 3; c3++)
      kk[c3].u = *reinterpret_cast<const uint4*>(Kp + (t + c3 * 256) * 8);
  }

  v4f acc[2][3][3] = {};

  for (int n = 0; n < 8; n++) {
    __syncthreads();                     // A: drains V(n) (landed: issued one
                                         // MFMA-phase ago) + prev Ks reads
    // repack K(n) with per-i aq scales into swizzled LDS (VALU + ds_write)
    float a0f[8], a1f[8];
    {
      U8 a0, a1;
      a0.u = *reinterpret_cast<const uint4*>(&aqs[n * 64 + colq]);
      a1.u = *reinterpret_cast<const uint4*>(&aqs[512 + n * 64 + colq]);
      #pragma unroll
      for (int e = 0; e < 8; e++) {
        a0f[e] = __bfloat162float(a0.h[e]);
        a1f[e] = __bfloat162float(a1.h[e]);
      }
    }
    #pragma unroll
    for (int c3 = 0; c3 < 3; c3++) {
      U8 s0, s1;
      #pragma unroll
      for (int e = 0; e < 8; e++) {
        const float kv = __bfloat162float(kk[c3].h[e]);
        s0.h[e] = __float2bfloat16(kv * a0f[e]);
        s1.h[e] = __float2bfloat16(kv * a1f[e]);
      }
      const int phys = (rowk + 32 * c3) * 64 + (l7 ^ krow7) * 8;
      *reinterpret_cast<uint4*>(&Ks0[phys]) = s0.u;
      *reinterpret_cast<uint4*>(&Ks1[phys]) = s1.u;
    }
    __syncthreads();                     // B: drains only LDS writes (cheap)
    // issue V(n+1) into the other buffer + prefetch kk(n+1): both have the
    // whole MFMA phase below to land before barrier A of iteration n+1.
    if (n < 7) {
      const bf16* Vp1 = VPb + (size_t)(n + 1) * 196608 + b * 6144;
      const int voff = 12288 + ((n + 1) & 1) * 6144;
      #pragma unroll
      for (int c = 0; c < 3; c++)
        async_cp16(&smem[voff + (w * 3 + c) * 512],
                   Vp1 + ((w * 3 + c) * 8 + l8) * 64 + (l7 ^ l8) * 8);
      const bf16* Kp1 = KPb + (size_t)(n + 1) * 196608 + b * 6144;
      #pragma unroll
      for (int c3 = 0; c3 < 3; c3++)
        kk[c3].u = *reinterpret_cast<const uint4*>(Kp1 + (t + c3 * 256) * 8);
    }

    const bf16* Vsn = smem + 12288 + (n & 1) * 6144;
    #pragma unroll
    for (int s = 0; s < 2; s++) {
      const int pc = ((s * 4 + q) ^ (m16 & 7)) * 8;
      short8 bfr[3], af0[3], af1[3];
      #pragma unroll
      for (int cc = 0; cc < 3; cc++)
        bfr[cc] = *reinterpret_cast<const short8*>(
            &Vsn[(wc * 48 + cc * 16 + m16) * 64 + pc]);
      #pragma unroll
      for (int a = 0; a < 3; a++) {
        af0[a] = *reinterpret_cast<const short8*>(
            &Ks0[(wr * 48 + a * 16 + m16) * 64 + pc]);
        af1[a] = *reinterpret_cast<const short8*>(
            &Ks1[(wr * 48 + a * 16 + m16) * 64 + pc]);
      }
      #pragma unroll
      for (int a = 0; a < 3; a++)
        #pragma unroll
        for (int cc = 0; cc < 3; cc++) {
          acc[0][a][cc] = __builtin_amdgcn_mfma_f32_16x16x32_bf16(
              af0[a], bfr[cc], acc[0][a][cc], 0, 0, 0);
          acc[1][a][cc] = __builtin_amdgcn_mfma_f32_16x16x32_bf16(
              af1[a], bfr[cc], acc[1][a][cc], 0, 0, 0);
        }
    }
  }

  // epilogue: assemble rows in LDS, then coalesced 16B global stores
  __syncthreads();
  #pragma unroll
  for (int isel = 0; isel < 2; isel++)
    #pragma unroll
    for (int a = 0; a < 3; a++)
      #pragma unroll
      for (int cc = 0; cc < 3; cc++) {
        const int j0 = wr * 48 + a * 16, k0c = wc * 48 + cc * 16;
        #pragma unroll
        for (int r = 0; r < 4; r++)
          smem[isel * 9216 + (j0 + q * 4 + r) * 96 + k0c + m16] =
              __float2bfloat16(acc[isel][a][cc][r]);
      }
  __syncthreads();
  const size_t obase = (size_t)(b * 96 + i0) * 9216;
  #pragma unroll
  for (int c = t; c < 2304; c += 256)
    *reinterpret_cast<uint4*>(FULL + obase + c * 8) =
        *reinterpret_cast<const uint4*>(&smem[c * 8]);
}

// ------- stage C (R12 proven): 128x64, BK=64, split-K=4, 1-barrier dbuf -----
// LDS rows: 64 bf16 = 128 B = 8 chunks; phys chunk = logical ^ (row & 7)
__global__ __launch_bounds__(256) void stage_c_mfma(
    const bf16* __restrict__ FULL, const bf16* __restrict__ WoT,
    float* __restrict__ out) {
  const int bm = blockIdx.x * 128, bn = blockIdx.y * 64;
  const int kbase = blockIdx.z * 2304;
  __shared__ __align__(16) bf16 As[2][128 * 64];   // 16 KB each
  __shared__ __align__(16) bf16 Bs[2][64 * 64];    //  8 KB each  (48 KB total)
  const int t = threadIdx.x;
  const int w = t >> 6, lane = t & 63;
  const int m16 = lane & 15, q = lane >> 4;
  const int l8 = lane >> 3, l7 = lane & 7;

  v4f acc[2][4] = {};

#define SC_STAGE(buf, k0)                                                    \
  {                                                                          \
    _Pragma("unroll")                                                        \
    for (int c = 0; c < 4; c++) {                                            \
      const int r0 = (w * 4 + c) * 8;                                        \
      async_cp16(&As[buf][(w * 4 + c) * 512],                                \
                 FULL + (size_t)(bm + r0 + l8) * 9216 + (k0) + (l7 ^ l8) * 8); \
    }                                                                        \
    _Pragma("unroll")                                                        \
    for (int c = 0; c < 2; c++) {                                            \
      const int r0 = (w * 2 + c) * 8;                                        \
      async_cp16(&Bs[buf][(w * 2 + c) * 512],                                \
                 WoT + (size_t)(bn + r0 + l8) * 9216 + (k0) + (l7 ^ l8) * 8);  \
    }                                                                        \
  }

#define SC_COMPUTE(buf)                                                      \
  {                                                                          \
    _Pragma("unroll")                                                        \
    for (int s = 0; s < 2; s++) {                                            \
      const int pc = ((s * 4 + q) ^ (m16 & 7)) * 8;                          \
      short8 af[2], bfr[4];                                                  \
      _Pragma("unroll")                                                      \
      for (int mt = 0; mt < 2; mt++)                                         \
        af[mt] = *reinterpret_cast<const short8*>(                           \
            &As[buf][(w * 32 + mt * 16 + m16) * 64 + pc]);                   \
      _Pragma("unroll")                                                      \
      for (int nt = 0; nt < 4; nt++)                                         \
        bfr[nt] = *reinterpret_cast<const short8*>(                          \
            &Bs[buf][(nt * 16 + m16) * 64 + pc]);                            \
      _Pragma("unroll")                                                      \
      for (int mt = 0; mt < 2; mt++)                                         \
        _Pragma("unroll")                                                    \
        for (int nt = 0; nt < 4; nt++)                                       \
          acc[mt][nt] = __builtin_amdgcn_mfma_f32_16x16x32_bf16(             \
              af[mt], bfr[nt], acc[mt][nt], 0, 0, 0);                        \
    }                                                                        \
  }

  SC_STAGE(0, kbase);                 // prologue: step 0 into buf 0
  __syncthreads();

  for (int it = 0; it < 18; it++) {   // steps 2it (buf0) and 2it+1 (buf1)
    SC_STAGE(1, kbase + (2 * it + 1) * 64);
    SC_COMPUTE(0);
    __syncthreads();
    if (it < 17) SC_STAGE(0, kbase + (2 * it + 2) * 64);
    SC_COMPUTE(1);
    __syncthreads();
  }

  #pragma unroll
  for (int mt = 0; mt < 2; mt++)
    #pragma unroll
    for (int nt = 0; nt < 4; nt++)
      #pragma unroll
      for (int r = 0; r < 4; r++) {
        const int row = bm + w * 32 + mt * 16 + q * 4 + r;
        const int col = bn + nt * 16 + m16;
        atomicAdd(&out[(size_t)row * 512 + col], acc[mt][nt][r]);
      }
#undef SC_STAGE
#undef SC_COMPUTE
}

extern "C" void kernel_launch(void* const* d_in, const int* in_sizes, int n_in,
                              void* d_out, int out_size, void* d_ws, size_t ws_size,
                              hipStream_t stream) {
  const float* queries = (const float*)d_in[0];
  const float* keys    = (const float*)d_in[1];
  const float* values  = (const float*)d_in[2];
  // d_in[3] = attn_mask (unused by reference)
  const float* Wq   = (const float*)d_in[4];
  const float* bq   = (const float*)d_in[5];
  const float* Wk   = (const float*)d_in[6];
  const float* bk   = (const float*)d_in[7];
  const float* Wv   = (const float*)d_in[8];
  const float* bv   = (const float*)d_in[9];
  const float* core = (const float*)d_in[10];
  const float* Wo   = (const float*)d_in[11];
  const float* bo   = (const float*)d_in[12];
  float* out = (float*)d_out;

  char* ws = (char*)d_ws;
  bf16* AQb = (bf16*)(ws);                   // 3.15 MB (3072*512) = core*q/8
  bf16* KPb = (bf16*)(ws + 3145728);         // 3.15 MB
  bf16* VPb = (bf16*)(ws + 6291456);         // 3.15 MB
  bf16* WTq = (bf16*)(ws + 9437184);         // 0.52 MB (512*512)
  bf16* WTk = (bf16*)(ws + 9961472);         // 0.52 MB
  bf16* WTv = (bf16*)(ws + 10485760);        // 0.52 MB
  bf16* WoT = (bf16*)(ws + 11010048);        // 9.44 MB (512*9216)
  bf16* FULL = (bf16*)(ws + 20447232);       // 56.62 MB (3072*9216)
  // Xb* overlay the FULL region: proj reads them before stage_b writes FULL.
  bf16* Xbq = FULL;
  bf16* Xbk = FULL + 1572864;
  bf16* Xbv = FULL + 3145728;

  prep<<<dim3(5376), dim3(256), 0, stream>>>(
      Wo, Wq, Wk, Wv, queries, keys, values, bo,
      WoT, WTq, WTk, WTv, Xbq, Xbk, Xbv, out);

  proj_mfma<<<dim3(48, 8, 3), dim3(128), 0, stream>>>(
      Xbq, Xbk, Xbv, WTq, WTk, WTv, bq, bk, bv, core, AQb, KPb, VPb);

  stage_b_mfma<<<dim3(48, 32), dim3(256), 0, stream>>>(AQb, KPb, VPb, FULL);

  stage_c_mfma<<<dim3(24, 8, 4), dim3(256), 0, stream>>>(FULL, WoT, out);
}